// Round 1
// baseline (632.760 us; speedup 1.0000x reference)
//
#include <hip/hip_runtime.h>

typedef short bf16x8 __attribute__((ext_vector_type(8)));
typedef float f32x4 __attribute__((ext_vector_type(4)));

#define HID   2048
#define S_LEN 2048
#define NH    16
#define HD    128
#define BATCH 2
#define NROWS (BATCH * S_LEN)  // 4096

__device__ __forceinline__ float bf2f(unsigned short u) {
    union { unsigned int i; float f; } v;
    v.i = ((unsigned int)u) << 16;
    return v.f;
}
__device__ __forceinline__ unsigned short f2bf(float f) {
    union { float f; unsigned int i; } v;
    v.f = f;
    unsigned int u = v.i;
    return (unsigned short)((u + 0x7fffu + ((u >> 16) & 1u)) >> 16);
}

// ---------------- cast fp32 -> bf16 ----------------
__global__ __launch_bounds__(256) void cast_f32_bf16(const float* __restrict__ x,
                                                     unsigned short* __restrict__ y, int n) {
    int i = (blockIdx.x * 256 + threadIdx.x) * 4;
    if (i < n) {
        float4 v = *(const float4*)(x + i);
        ushort4 o;
        o.x = f2bf(v.x); o.y = f2bf(v.y); o.z = f2bf(v.z); o.w = f2bf(v.w);
        *(ushort4*)(y + i) = o;
    }
}

// ---------------- transpose + cast: W[k][o] fp32 -> WT[o][k] bf16 ----------------
__global__ __launch_bounds__(256) void transpose_cast(const float* __restrict__ W,
                                                      unsigned short* __restrict__ WT) {
    __shared__ float tile[32][33];
    int tx = threadIdx.x, ty = threadIdx.y;  // 32 x 8
    int bx = blockIdx.x, by = blockIdx.y;
#pragma unroll
    for (int i = 0; i < 4; i++)
        tile[ty + i * 8][tx] = W[(size_t)(by * 32 + ty + i * 8) * HID + bx * 32 + tx];
    __syncthreads();
#pragma unroll
    for (int i = 0; i < 4; i++)
        WT[(size_t)(bx * 32 + ty + i * 8) * HID + by * 32 + tx] = f2bf(tile[tx][ty + i * 8]);
}

// ---------------- bf16 GEMM: C[m][n] = sum_k A[m][k] * Bt[n][k] ----------------
// MODE 0: write bf16 to [b][h][s][d]   (Q, K)
// MODE 1: write bf16 to [b][h][d][s]   (V transposed)
// MODE 2: write fp32 to [row][col]     (final output)
template <int MODE>
__global__ __launch_bounds__(256) void gemm_bt(const unsigned short* __restrict__ A,
                                               const unsigned short* __restrict__ Bt,
                                               void* __restrict__ Cout) {
    const int K = HID, N = HID;
    __shared__ unsigned short Asm[128][40];
    __shared__ unsigned short Bsm[128][40];
    int t = threadIdx.x;
    int wave = t >> 6, lane = t & 63;
    int wm = wave >> 1, wn = wave & 1;
    int c = lane & 15, quad = lane >> 4;
    int m0 = blockIdx.y * 128, n0 = blockIdx.x * 128;

    f32x4 zero = {0.f, 0.f, 0.f, 0.f};
    f32x4 acc[4][4];
#pragma unroll
    for (int i = 0; i < 4; i++)
#pragma unroll
        for (int j = 0; j < 4; j++) acc[i][j] = zero;

    for (int k0 = 0; k0 < K; k0 += 32) {
#pragma unroll
        for (int l = 0; l < 2; l++) {
            int flat = l * 2048 + t * 8;
            int row = flat >> 5, col = flat & 31;
            bf16x8 av = *(const bf16x8*)(A + (size_t)(m0 + row) * K + k0 + col);
            *(bf16x8*)(&Asm[row][col]) = av;
            bf16x8 bv = *(const bf16x8*)(Bt + (size_t)(n0 + row) * K + k0 + col);
            *(bf16x8*)(&Bsm[row][col]) = bv;
        }
        __syncthreads();
        bf16x8 af[4], bfr[4];
#pragma unroll
        for (int mt = 0; mt < 4; mt++)
            af[mt] = *(const bf16x8*)(&Asm[wm * 64 + mt * 16 + c][quad * 8]);
#pragma unroll
        for (int nt = 0; nt < 4; nt++)
            bfr[nt] = *(const bf16x8*)(&Bsm[wn * 64 + nt * 16 + c][quad * 8]);
#pragma unroll
        for (int mt = 0; mt < 4; mt++)
#pragma unroll
            for (int nt = 0; nt < 4; nt++)
                acc[mt][nt] = __builtin_amdgcn_mfma_f32_16x16x32_bf16(af[mt], bfr[nt],
                                                                      acc[mt][nt], 0, 0, 0);
        __syncthreads();
    }

#pragma unroll
    for (int mt = 0; mt < 4; mt++) {
#pragma unroll
        for (int nt = 0; nt < 4; nt++) {
#pragma unroll
            for (int r = 0; r < 4; r++) {
                int row = m0 + wm * 64 + mt * 16 + quad * 4 + r;
                int col = n0 + wn * 64 + nt * 16 + c;
                float v = acc[mt][nt][r];
                if (MODE == 2) {
                    ((float*)Cout)[(size_t)row * N + col] = v;
                } else {
                    int b = row >> 11, s = row & 2047;
                    int h = col >> 7, d = col & 127;
                    size_t idx;
                    if (MODE == 0) idx = ((size_t)(b * NH + h) * S_LEN + s) * HD + d;
                    else           idx = ((size_t)(b * NH + h) * HD + d) * S_LEN + s;
                    ((unsigned short*)Cout)[idx] = f2bf(v);
                }
            }
        }
    }
}

// ---------------- RoPE in place on Q and K ([b][h][s][d] bf16) ----------------
__global__ __launch_bounds__(256) void rope_kernel(unsigned short* __restrict__ Qb,
                                                   unsigned short* __restrict__ Kb,
                                                   const float* __restrict__ cosp,
                                                   const float* __restrict__ sinp) {
    unsigned short* P = blockIdx.y ? Kb : Qb;
    int idx = blockIdx.x * 256 + threadIdx.x;  // pair index over B*H*S*64
    int row = idx >> 6, j = idx & 63;
    int s = row & (S_LEN - 1);
    size_t base = (size_t)row * HD;
    float x1 = bf2f(P[base + j]);
    float x2 = bf2f(P[base + j + 64]);
    float c1 = cosp[s * HD + j], s1 = sinp[s * HD + j];
    float c2 = cosp[s * HD + j + 64], s2 = sinp[s * HD + j + 64];
    P[base + j]      = f2bf(x1 * c1 - x2 * s1);  // rot[j]    = -x[j+64]
    P[base + j + 64] = f2bf(x2 * c2 + x1 * s2);  // rot[j+64] =  x[j]
}

// ---------------- flash attention ----------------
// Q,K: [b][h][s][d] bf16 (RoPE'd).  Vt: [b][h][d][s] bf16.  Aout: [b*s][h*d] bf16.
__global__ __launch_bounds__(256) void attn_kernel(const unsigned short* __restrict__ Q,
                                                   const unsigned short* __restrict__ Kg,
                                                   const unsigned short* __restrict__ Vt,
                                                   unsigned short* __restrict__ Aout) {
    __shared__ unsigned short Ksm[32][136];     // [key][dim], pad for b128 reads
    __shared__ unsigned short Vsm[128][40];     // [dim][key]
    __shared__ unsigned short Psm[4][16][40];   // per-wave P tile [qrow][key]
    int bh = blockIdx.y;
    int b = bh >> 4, h = bh & 15;
    int t = threadIdx.x;
    int wave = t >> 6, lane = t & 63;
    int c = lane & 15, quad = lane >> 4;
    int q0 = blockIdx.x * 64 + wave * 16;
    const unsigned short* Qp = Q + (size_t)bh * S_LEN * HD;
    const unsigned short* Kp = Kg + (size_t)bh * S_LEN * HD;
    const unsigned short* Vp = Vt + (size_t)bh * HD * S_LEN;

    bf16x8 qf[4];
#pragma unroll
    for (int kk = 0; kk < 4; kk++)
        qf[kk] = *(const bf16x8*)(Qp + (size_t)(q0 + c) * HD + kk * 32 + quad * 8);

    f32x4 zero = {0.f, 0.f, 0.f, 0.f};
    f32x4 o_acc[8];
#pragma unroll
    for (int i = 0; i < 8; i++) o_acc[i] = zero;
    float mrun[4], lrun[4];
#pragma unroll
    for (int r = 0; r < 4; r++) { mrun[r] = -1e30f; lrun[r] = 0.0f; }

    const float sc = 0.08838834764831845f;  // 1/sqrt(128)

    for (int key0 = 0; key0 < S_LEN; key0 += 32) {
        // stage K chunk (contiguous 8KB) and Vt chunk
#pragma unroll
        for (int l = 0; l < 2; l++) {
            int flat = l * 2048 + t * 8;
            {
                int row = flat >> 7, col = flat & 127;
                bf16x8 kv = *(const bf16x8*)(Kp + (size_t)key0 * HD + flat);
                *(bf16x8*)(&Ksm[row][col]) = kv;
            }
            {
                int row = flat >> 5, col = flat & 31;
                bf16x8 vv = *(const bf16x8*)(Vp + (size_t)row * S_LEN + key0 + col);
                *(bf16x8*)(&Vsm[row][col]) = vv;
            }
        }
        __syncthreads();

        // S = Q K^T for 16 q-rows x 32 keys
        f32x4 sacc[2];
        sacc[0] = zero; sacc[1] = zero;
#pragma unroll
        for (int kk = 0; kk < 4; kk++)
#pragma unroll
            for (int nt = 0; nt < 2; nt++) {
                bf16x8 kfrag = *(const bf16x8*)(&Ksm[nt * 16 + c][kk * 32 + quad * 8]);
                sacc[nt] = __builtin_amdgcn_mfma_f32_16x16x32_bf16(qf[kk], kfrag,
                                                                   sacc[nt], 0, 0, 0);
            }

        // online softmax (rows owned: quad*4 + r)
        float p0v[4], p1v[4], rmax[4], rsum[4];
#pragma unroll
        for (int r = 0; r < 4; r++) {
            p0v[r] = sacc[0][r] * sc;
            p1v[r] = sacc[1][r] * sc;
            rmax[r] = fmaxf(p0v[r], p1v[r]);
        }
#pragma unroll
        for (int off = 1; off < 16; off <<= 1)
#pragma unroll
            for (int r = 0; r < 4; r++)
                rmax[r] = fmaxf(rmax[r], __shfl_xor(rmax[r], off));
        float alpha[4];
#pragma unroll
        for (int r = 0; r < 4; r++) {
            float mnew = fmaxf(mrun[r], rmax[r]);
            alpha[r] = __expf(mrun[r] - mnew);
            mrun[r] = mnew;
            float e0 = __expf(p0v[r] - mnew);
            float e1 = __expf(p1v[r] - mnew);
            rsum[r] = e0 + e1;
            Psm[wave][quad * 4 + r][c]      = f2bf(e0);
            Psm[wave][quad * 4 + r][16 + c] = f2bf(e1);
        }
#pragma unroll
        for (int off = 1; off < 16; off <<= 1)
#pragma unroll
            for (int r = 0; r < 4; r++)
                rsum[r] += __shfl_xor(rsum[r], off);
#pragma unroll
        for (int r = 0; r < 4; r++) lrun[r] = lrun[r] * alpha[r] + rsum[r];
#pragma unroll
        for (int i = 0; i < 8; i++)
#pragma unroll
            for (int r = 0; r < 4; r++) o_acc[i][r] *= alpha[r];
        __syncthreads();  // Psm visibility

        // O += P V   (P: A-layout from LDS; Vt: B-layout, contiguous keys)
        bf16x8 pf = *(const bf16x8*)(&Psm[wave][c][quad * 8]);
#pragma unroll
        for (int nt = 0; nt < 8; nt++) {
            bf16x8 vfr = *(const bf16x8*)(&Vsm[nt * 16 + c][quad * 8]);
            o_acc[nt] = __builtin_amdgcn_mfma_f32_16x16x32_bf16(pf, vfr, o_acc[nt], 0, 0, 0);
        }
        __syncthreads();  // before next-iter staging overwrites Ksm/Vsm
    }

    // epilogue: divide by l, write bf16 to Aout[b*S+s][h*128+d]
#pragma unroll
    for (int r = 0; r < 4; r++) {
        float inv = 1.0f / lrun[r];
        int srow = q0 + quad * 4 + r;
        size_t base = ((size_t)(b * S_LEN + srow)) * HID + h * HD;
#pragma unroll
        for (int nt = 0; nt < 8; nt++)
            Aout[base + nt * 16 + c] = f2bf(o_acc[nt][r] * inv);
    }
}

extern "C" void kernel_launch(void* const* d_in, const int* in_sizes, int n_in,
                              void* d_out, int out_size, void* d_ws, size_t ws_size,
                              hipStream_t stream) {
    const float* hs   = (const float*)d_in[0];
    const float* cosp = (const float*)d_in[1];
    const float* sinp = (const float*)d_in[2];
    const float* Wq   = (const float*)d_in[3];
    const float* Wk   = (const float*)d_in[4];
    const float* Wv   = (const float*)d_in[5];
    const float* Wo   = (const float*)d_in[6];

    char* ws = (char*)d_ws;
    unsigned short* Xb = (unsigned short*)(ws);                      // 16 MB (reused as Aout)
    unsigned short* WT = (unsigned short*)(ws + (16ull << 20));      // 8 MB (reused per weight)
    unsigned short* Qb = (unsigned short*)(ws + (24ull << 20));      // 16 MB
    unsigned short* Kb = (unsigned short*)(ws + (40ull << 20));      // 16 MB
    unsigned short* Vb = (unsigned short*)(ws + (56ull << 20));      // 16 MB  (total 72 MB)

    dim3 tb(32, 8);
    dim3 tg(64, 64);
    dim3 gg(16, 32);  // (N/128, M/128)

    cast_f32_bf16<<<8192, 256, 0, stream>>>(hs, Xb, NROWS * HID);

    transpose_cast<<<tg, tb, 0, stream>>>(Wq, WT);
    gemm_bt<0><<<gg, 256, 0, stream>>>(Xb, WT, Qb);

    transpose_cast<<<tg, tb, 0, stream>>>(Wk, WT);
    gemm_bt<0><<<gg, 256, 0, stream>>>(Xb, WT, Kb);

    transpose_cast<<<tg, tb, 0, stream>>>(Wv, WT);
    gemm_bt<1><<<gg, 256, 0, stream>>>(Xb, WT, Vb);

    rope_kernel<<<dim3(16384, 2), 256, 0, stream>>>(Qb, Kb, cosp, sinp);

    attn_kernel<<<dim3(32, 32), 256, 0, stream>>>(Qb, Kb, Vb, Xb /*Aout*/);

    transpose_cast<<<tg, tb, 0, stream>>>(Wo, WT);
    gemm_bt<2><<<gg, 256, 0, stream>>>(Xb, WT, d_out);
}

// Round 2
// 448.627 us; speedup vs baseline: 1.4104x; 1.4104x over previous
//
#include <hip/hip_runtime.h>

typedef short bf16x8 __attribute__((ext_vector_type(8)));
typedef float f32x4 __attribute__((ext_vector_type(4)));

#define HID   2048
#define S_LEN 2048
#define NH    16
#define HD    128
#define BATCH 2
#define NROWS (BATCH * S_LEN)  // 4096

__device__ __forceinline__ float bf2f(unsigned short u) {
    union { unsigned int i; float f; } v;
    v.i = ((unsigned int)u) << 16;
    return v.f;
}
__device__ __forceinline__ unsigned short f2bf(float f) {
    union { float f; unsigned int i; } v;
    v.f = f;
    unsigned int u = v.i;
    return (unsigned short)((u + 0x7fffu + ((u >> 16) & 1u)) >> 16);
}

// async global->LDS, 16B per lane. LDS dest = wave-uniform base + lane*16B.
__device__ __forceinline__ void async16(const unsigned short* g, unsigned short* l) {
    __builtin_amdgcn_global_load_lds(
        (const __attribute__((address_space(1))) unsigned int*)g,
        (__attribute__((address_space(3))) unsigned int*)l, 16, 0, 0);
}

// ---------------- cast fp32 -> bf16 ----------------
__global__ __launch_bounds__(256) void cast_f32_bf16(const float* __restrict__ x,
                                                     unsigned short* __restrict__ y, int n) {
    int i = (blockIdx.x * 256 + threadIdx.x) * 4;
    if (i < n) {
        float4 v = *(const float4*)(x + i);
        ushort4 o;
        o.x = f2bf(v.x); o.y = f2bf(v.y); o.z = f2bf(v.z); o.w = f2bf(v.w);
        *(ushort4*)(y + i) = o;
    }
}

// ---------------- transpose + cast: W[k][o] fp32 -> WT[o][k] bf16 ----------------
__global__ __launch_bounds__(256) void transpose_cast(const float* __restrict__ W,
                                                      unsigned short* __restrict__ WT) {
    __shared__ float tile[32][33];
    int tx = threadIdx.x, ty = threadIdx.y;  // 32 x 8
    int bx = blockIdx.x, by = blockIdx.y;
#pragma unroll
    for (int i = 0; i < 4; i++)
        tile[ty + i * 8][tx] = W[(size_t)(by * 32 + ty + i * 8) * HID + bx * 32 + tx];
    __syncthreads();
#pragma unroll
    for (int i = 0; i < 4; i++)
        WT[(size_t)(bx * 32 + ty + i * 8) * HID + by * 32 + tx] = f2bf(tile[tx][ty + i * 8]);
}

// ---------------- bf16 GEMM (m97-style): C[m][n] = sum_k A[m][k] * Bt[n][k] ----------------
// MODE 0: write bf16 to [b][h][s][d]   (Q, K)
// MODE 1: write bf16 to [b][h][d][s]   (V transposed)
// MODE 2: write fp32 to [row][col]     (final output)
template <int MODE>
__global__ __launch_bounds__(256, 2) void gemm_bt(const unsigned short* __restrict__ A,
                                                  const unsigned short* __restrict__ Bt,
                                                  void* __restrict__ Cout) {
    __shared__ unsigned short Asm[128 * 32];  // unpadded: required by global_load_lds
    __shared__ unsigned short Bsm[128 * 32];
    int t = threadIdx.x;
    int wave = t >> 6, lane = t & 63;
    int wm = wave >> 1, wn = wave & 1;
    int c = lane & 15, quad = lane >> 4;
    int m0 = blockIdx.y * 128, n0 = blockIdx.x * 128;

    // staging: wave w covers rows w*32..w*32+31, lane -> (row = w*32 + lane/4, col8 = lane%4)
    int srow = wave * 32 + (lane >> 2);
    int scol = (lane & 3) * 8;
    const unsigned short* Ag = A + (size_t)(m0 + srow) * HID + scol;
    const unsigned short* Bg = Bt + (size_t)(n0 + srow) * HID + scol;
    unsigned short* Al = Asm + wave * 1024;
    unsigned short* Bl = Bsm + wave * 1024;

    f32x4 zero = {0.f, 0.f, 0.f, 0.f};
    f32x4 acc[4][4];
#pragma unroll
    for (int i = 0; i < 4; i++)
#pragma unroll
        for (int j = 0; j < 4; j++) acc[i][j] = zero;

    for (int k0 = 0; k0 < HID; k0 += 32) {
        async16(Ag + k0, Al);
        async16(Ag + k0 + 16 * HID, Al + 512);
        async16(Bg + k0, Bl);
        async16(Bg + k0 + 16 * HID, Bl + 512);
        __syncthreads();
        bf16x8 af[4], bfr[4];
#pragma unroll
        for (int mt = 0; mt < 4; mt++)
            af[mt] = *(const bf16x8*)(Asm + (wm * 64 + mt * 16 + c) * 32 + quad * 8);
#pragma unroll
        for (int nt = 0; nt < 4; nt++)
            bfr[nt] = *(const bf16x8*)(Bsm + (wn * 64 + nt * 16 + c) * 32 + quad * 8);
#pragma unroll
        for (int mt = 0; mt < 4; mt++)
#pragma unroll
            for (int nt = 0; nt < 4; nt++)
                acc[mt][nt] = __builtin_amdgcn_mfma_f32_16x16x32_bf16(af[mt], bfr[nt],
                                                                      acc[mt][nt], 0, 0, 0);
        __syncthreads();
    }

#pragma unroll
    for (int mt = 0; mt < 4; mt++) {
#pragma unroll
        for (int nt = 0; nt < 4; nt++) {
#pragma unroll
            for (int r = 0; r < 4; r++) {
                int row = m0 + wm * 64 + mt * 16 + quad * 4 + r;
                int col = n0 + wn * 64 + nt * 16 + c;
                float v = acc[mt][nt][r];
                if (MODE == 2) {
                    ((float*)Cout)[(size_t)row * HID + col] = v;
                } else {
                    int b = row >> 11, s = row & 2047;
                    int h = col >> 7, d = col & 127;
                    size_t idx;
                    if (MODE == 0) idx = ((size_t)(b * NH + h) * S_LEN + s) * HD + d;
                    else           idx = ((size_t)(b * NH + h) * HD + d) * S_LEN + s;
                    ((unsigned short*)Cout)[idx] = f2bf(v);
                }
            }
        }
    }
}

// ---------------- RoPE in place; Q additionally pre-scaled by 1/sqrt(D) ----------------
__global__ __launch_bounds__(256) void rope_kernel(unsigned short* __restrict__ Qb,
                                                   unsigned short* __restrict__ Kb,
                                                   const float* __restrict__ cosp,
                                                   const float* __restrict__ sinp) {
    unsigned short* P = blockIdx.y ? Kb : Qb;
    float scq = blockIdx.y ? 1.0f : 0.08838834764831845f;
    int idx = blockIdx.x * 256 + threadIdx.x;  // pair index over B*H*S*64
    int row = idx >> 6, j = idx & 63;
    int s = row & (S_LEN - 1);
    size_t base = (size_t)row * HD;
    float x1 = bf2f(P[base + j]);
    float x2 = bf2f(P[base + j + 64]);
    float c1 = cosp[s * HD + j], s1 = sinp[s * HD + j];
    float c2 = cosp[s * HD + j + 64], s2 = sinp[s * HD + j + 64];
    P[base + j]      = f2bf((x1 * c1 - x2 * s1) * scq);
    P[base + j + 64] = f2bf((x2 * c2 + x1 * s2) * scq);
}

// ---------------- flash attention (no-max online softmax, S^T formulation) ----------------
// Q,K: [b][h][s][d] bf16 (Q pre-scaled).  Vt: [b][h][d][s] bf16.  Aout: [b*s][h*d] bf16.
// Block: 4 waves x 32 q-rows = 128 q-rows. Key chunks of 64.
#define PKS 72  // P row stride in shorts (144B = 9*16: b128-aligned, conflict-free)
__global__ __launch_bounds__(256, 2) void attn_kernel(const unsigned short* __restrict__ Q,
                                                      const unsigned short* __restrict__ Kg,
                                                      const unsigned short* __restrict__ Vt,
                                                      unsigned short* __restrict__ Aout) {
    __shared__ unsigned short Ksm[64 * 128];            // 16 KB, [key][d], XOR-swizzled chunks
    __shared__ unsigned short Vsm[128 * 64];            // 16 KB, [d][key], XOR-swizzled chunks
    __shared__ __align__(16) unsigned short Psm[4 * 2 * 16 * PKS];  // 18 KB
    int bh = blockIdx.y;
    int b = bh >> 4, h = bh & 15;
    int t = threadIdx.x;
    int wave = t >> 6, lane = t & 63;
    int c = lane & 15, quad = lane >> 4;
    int q0 = blockIdx.x * 128 + wave * 32;
    const unsigned short* Qp = Q + (size_t)bh * S_LEN * HD;
    const unsigned short* Kp = Kg + (size_t)bh * S_LEN * HD;
    const unsigned short* Vp = Vt + (size_t)bh * HD * S_LEN;

    // persistent Q fragments: 2 n-tiles (32 q-rows) x 4 k-frags
    bf16x8 qf[2][4];
#pragma unroll
    for (int qn = 0; qn < 2; qn++)
#pragma unroll
        for (int kk = 0; kk < 4; kk++)
            qf[qn][kk] = *(const bf16x8*)(Qp + (size_t)(q0 + qn * 16 + c) * HD + kk * 32 + quad * 8);

    f32x4 zero = {0.f, 0.f, 0.f, 0.f};
    f32x4 o_acc[2][8];
#pragma unroll
    for (int qn = 0; qn < 2; qn++)
#pragma unroll
        for (int nt = 0; nt < 8; nt++) o_acc[qn][nt] = zero;
    float lsum[2] = {0.f, 0.f};

    for (int key0 = 0; key0 < S_LEN; key0 += 64) {
        // stage K[64][128] and Vt[128][64] chunks via async DMA, XOR-swizzled source
#pragma unroll
        for (int j = 0; j < 4; j++) {
            int fc = (wave * 4 + j) * 64 + lane;
            int rK = fc >> 4, cbK = (fc & 15) ^ (rK & 15);
            async16(Kp + (size_t)(key0 + rK) * HD + cbK * 8, Ksm + (wave * 4 + j) * 512);
            int rV = fc >> 3, cbV = (fc & 7) ^ (rV & 7);
            async16(Vp + (size_t)rV * S_LEN + key0 + cbV * 8, Vsm + (wave * 4 + j) * 512);
        }
        __syncthreads();

        // S^T = K * Q^T : M=key (4 tiles), N=qrow (2 tiles), K=d (4 frags)
        f32x4 sacc[4][2];
#pragma unroll
        for (int km = 0; km < 4; km++)
#pragma unroll
            for (int qn = 0; qn < 2; qn++) sacc[km][qn] = zero;
#pragma unroll
        for (int kk = 0; kk < 4; kk++) {
            bf16x8 kfr[4];
#pragma unroll
            for (int km = 0; km < 4; km++)
                kfr[km] = *(const bf16x8*)(Ksm + (km * 16 + c) * HD + (((kk * 4 + quad) ^ c)) * 8);
#pragma unroll
            for (int km = 0; km < 4; km++)
#pragma unroll
                for (int qn = 0; qn < 2; qn++)
                    sacc[km][qn] = __builtin_amdgcn_mfma_f32_16x16x32_bf16(kfr[km], qf[qn][kk],
                                                                           sacc[km][qn], 0, 0, 0);
        }

        // exp (no max subtraction), accumulate row-sum partials, pack P -> LDS
        // C-layout of S^T: lane holds qrow=c, keys km*16 + quad*4 + r (consecutive r!)
#pragma unroll
        for (int qn = 0; qn < 2; qn++) {
#pragma unroll
            for (int km = 0; km < 4; km++) {
                float e0 = __expf(sacc[km][qn][0]);
                float e1 = __expf(sacc[km][qn][1]);
                float e2 = __expf(sacc[km][qn][2]);
                float e3 = __expf(sacc[km][qn][3]);
                lsum[qn] += (e0 + e1) + (e2 + e3);
                uint2 pk;
                pk.x = (unsigned int)f2bf(e0) | ((unsigned int)f2bf(e1) << 16);
                pk.y = (unsigned int)f2bf(e2) | ((unsigned int)f2bf(e3) << 16);
                *(uint2*)(Psm + ((wave * 2 + qn) * 16 + c) * PKS + km * 16 + quad * 4) = pk;
            }
        }
        // intra-wave LDS write->read ordering (cross-lane): compiler fence + lgkmcnt(0)
        asm volatile("" ::: "memory");
        __builtin_amdgcn_s_waitcnt(0xc07f);  // lgkmcnt(0), vmcnt/expcnt unaffected
        asm volatile("" ::: "memory");

        // O += P * V : A=P [qrow][key], B=Vt [d][key]
#pragma unroll
        for (int kf = 0; kf < 2; kf++) {
            bf16x8 pf[2];
#pragma unroll
            for (int qn = 0; qn < 2; qn++)
                pf[qn] = *(const bf16x8*)(Psm + ((wave * 2 + qn) * 16 + c) * PKS + kf * 32 + quad * 8);
#pragma unroll
            for (int nt = 0; nt < 8; nt++) {
                bf16x8 vf = *(const bf16x8*)(Vsm + (nt * 16 + c) * 64 +
                                             (((kf * 4 + quad) ^ (c & 7))) * 8);
#pragma unroll
                for (int qn = 0; qn < 2; qn++)
                    o_acc[qn][nt] = __builtin_amdgcn_mfma_f32_16x16x32_bf16(pf[qn], vf,
                                                                            o_acc[qn][nt], 0, 0, 0);
            }
        }
        __syncthreads();  // protect Ksm/Vsm before next-iter DMA
    }

    // final: reduce lsum over the 4 quad-lanes (row = c), broadcast to C-layout rows
#pragma unroll
    for (int qn = 0; qn < 2; qn++) {
        lsum[qn] += __shfl_xor(lsum[qn], 16);
        lsum[qn] += __shfl_xor(lsum[qn], 32);
    }
    float inv[2][4];
#pragma unroll
    for (int qn = 0; qn < 2; qn++)
#pragma unroll
        for (int r = 0; r < 4; r++)
            inv[qn][r] = 1.0f / __shfl(lsum[qn], quad * 4 + r);

#pragma unroll
    for (int qn = 0; qn < 2; qn++) {
#pragma unroll
        for (int r = 0; r < 4; r++) {
            int srow = q0 + qn * 16 + quad * 4 + r;
            size_t base = ((size_t)(b * S_LEN + srow)) * HID + h * HD;
#pragma unroll
            for (int nt = 0; nt < 8; nt++)
                Aout[base + nt * 16 + c] = f2bf(o_acc[qn][nt][r] * inv[qn][r]);
        }
    }
}

extern "C" void kernel_launch(void* const* d_in, const int* in_sizes, int n_in,
                              void* d_out, int out_size, void* d_ws, size_t ws_size,
                              hipStream_t stream) {
    const float* hs   = (const float*)d_in[0];
    const float* cosp = (const float*)d_in[1];
    const float* sinp = (const float*)d_in[2];
    const float* Wq   = (const float*)d_in[3];
    const float* Wk   = (const float*)d_in[4];
    const float* Wv   = (const float*)d_in[5];
    const float* Wo   = (const float*)d_in[6];

    char* ws = (char*)d_ws;
    unsigned short* Xb = (unsigned short*)(ws);                      // 16 MB (reused as Aout)
    unsigned short* WT = (unsigned short*)(ws + (16ull << 20));      // 8 MB (reused per weight)
    unsigned short* Qb = (unsigned short*)(ws + (24ull << 20));      // 16 MB
    unsigned short* Kb = (unsigned short*)(ws + (40ull << 20));      // 16 MB
    unsigned short* Vb = (unsigned short*)(ws + (56ull << 20));      // 16 MB  (total 72 MB)

    dim3 tb(32, 8);
    dim3 tg(64, 64);
    dim3 gg(16, 32);  // (N/128, M/128)

    cast_f32_bf16<<<8192, 256, 0, stream>>>(hs, Xb, NROWS * HID);

    transpose_cast<<<tg, tb, 0, stream>>>(Wq, WT);
    gemm_bt<0><<<gg, 256, 0, stream>>>(Xb, WT, Qb);

    transpose_cast<<<tg, tb, 0, stream>>>(Wk, WT);
    gemm_bt<0><<<gg, 256, 0, stream>>>(Xb, WT, Kb);

    transpose_cast<<<tg, tb, 0, stream>>>(Wv, WT);
    gemm_bt<1><<<gg, 256, 0, stream>>>(Xb, WT, Vb);

    rope_kernel<<<dim3(16384, 2), 256, 0, stream>>>(Qb, Kb, cosp, sinp);

    attn_kernel<<<dim3(16, 32), 256, 0, stream>>>(Qb, Kb, Vb, Xb /*Aout*/);

    transpose_cast<<<tg, tb, 0, stream>>>(Wo, WT);
    gemm_bt<2><<<gg, 256, 0, stream>>>(Xb, WT, d_out);
}

// Round 3
// 422.747 us; speedup vs baseline: 1.4968x; 1.0612x over previous
//
#include <hip/hip_runtime.h>

typedef short bf16x8 __attribute__((ext_vector_type(8)));
typedef float f32x4 __attribute__((ext_vector_type(4)));

#define HID   2048
#define S_LEN 2048
#define NH    16
#define HD    128
#define BATCH 2
#define NROWS (BATCH * S_LEN)  // 4096

__device__ __forceinline__ float bf2f(unsigned short u) {
    union { unsigned int i; float f; } v;
    v.i = ((unsigned int)u) << 16;
    return v.f;
}
__device__ __forceinline__ unsigned short f2bf(float f) {
    union { float f; unsigned int i; } v;
    v.f = f;
    unsigned int u = v.i;
    return (unsigned short)((u + 0x7fffu + ((u >> 16) & 1u)) >> 16);
}

// packed f32x2 -> bf16x2 (RNE). Prefer HW v_cvt_pk_bf16_f32 on gfx950.
__device__ __forceinline__ unsigned int pkbf(float a, float b) {
#if defined(__has_builtin) && __has_builtin(__builtin_amdgcn_cvt_pk_bf16_f32)
    typedef __bf16 bf2_t __attribute__((ext_vector_type(2)));
    bf2_t v = __builtin_amdgcn_cvt_pk_bf16_f32(a, b);
    unsigned int u;
    __builtin_memcpy(&u, &v, 4);
    return u;
#else
    return (unsigned int)f2bf(a) | ((unsigned int)f2bf(b) << 16);
#endif
}

__device__ __forceinline__ float exp2_fast(float x) {
#if defined(__has_builtin) && __has_builtin(__builtin_amdgcn_exp2f)
    return __builtin_amdgcn_exp2f(x);
#else
    return __expf(x * 0.6931471805599453f);
#endif
}

// async global->LDS, 16B per lane. LDS dest = wave-uniform base + lane*16B.
__device__ __forceinline__ void async16(const unsigned short* g, unsigned short* l) {
    __builtin_amdgcn_global_load_lds(
        (const __attribute__((address_space(1))) unsigned int*)g,
        (__attribute__((address_space(3))) unsigned int*)l, 16, 0, 0);
}

// ---------------- cast fp32 -> bf16 ----------------
__global__ __launch_bounds__(256) void cast_f32_bf16(const float* __restrict__ x,
                                                     unsigned short* __restrict__ y, int n) {
    int i = (blockIdx.x * 256 + threadIdx.x) * 4;
    if (i < n) {
        float4 v = *(const float4*)(x + i);
        uint2 o;
        o.x = pkbf(v.x, v.y);
        o.y = pkbf(v.z, v.w);
        *(uint2*)(y + i) = o;
    }
}

// ---------------- transpose + cast: W[k][o] fp32 -> WT[z][o][k] bf16 ----------------
__global__ __launch_bounds__(256) void transpose_cast(const float* __restrict__ Wa,
                                                      const float* __restrict__ Wb,
                                                      const float* __restrict__ Wc,
                                                      unsigned short* __restrict__ WT) {
    __shared__ float tile[32][33];
    int tx = threadIdx.x, ty = threadIdx.y;  // 32 x 8
    int bx = blockIdx.x, by = blockIdx.y, z = blockIdx.z;
    const float* W = (z == 0) ? Wa : ((z == 1) ? Wb : Wc);
    unsigned short* dst = WT + (size_t)z * HID * HID;
#pragma unroll
    for (int i = 0; i < 4; i++)
        tile[ty + i * 8][tx] = W[(size_t)(by * 32 + ty + i * 8) * HID + bx * 32 + tx];
    __syncthreads();
#pragma unroll
    for (int i = 0; i < 4; i++)
        dst[(size_t)(bx * 32 + ty + i * 8) * HID + by * 32 + tx] = f2bf(tile[tx][ty + i * 8]);
}

// ---------------- bf16 GEMM (m97-style): C[m][nglob] = sum_k A[m][k] * Bt[nloc][k] ----------
// MODE 0: route by global col: mat 0 -> Qo [b][h][s][d], mat 1 -> Ko same, mat 2 -> Vo [b][h][d][s]
// MODE 2: write fp32 to Fo[row][col]
template <int MODE>
__global__ __launch_bounds__(256, 3) void gemm_bt(const unsigned short* __restrict__ A,
                                                  const unsigned short* __restrict__ Bt,
                                                  unsigned short* __restrict__ Qo,
                                                  unsigned short* __restrict__ Ko,
                                                  unsigned short* __restrict__ Vo,
                                                  float* __restrict__ Fo,
                                                  int n_shift) {
    __shared__ unsigned short Asm[128 * 32];  // unpadded: required by global_load_lds
    __shared__ unsigned short Bsm[128 * 32];
    int t = threadIdx.x;
    int wave = t >> 6, lane = t & 63;
    int wm = wave >> 1, wn = wave & 1;
    int c = lane & 15, quad = lane >> 4;
    int m0 = blockIdx.y * 128, nloc = blockIdx.x * 128;

    // staging: wave w covers rows w*32..w*32+31, lane -> (row = w*32 + lane/4, col8 = lane%4)
    int srow = wave * 32 + (lane >> 2);
    int scol = (lane & 3) * 8;
    const unsigned short* Ag = A + (size_t)(m0 + srow) * HID + scol;
    const unsigned short* Bg = Bt + (size_t)(nloc + srow) * HID + scol;
    unsigned short* Al = Asm + wave * 1024;
    unsigned short* Bl = Bsm + wave * 1024;

    f32x4 zero = {0.f, 0.f, 0.f, 0.f};
    f32x4 acc[4][4];
#pragma unroll
    for (int i = 0; i < 4; i++)
#pragma unroll
        for (int j = 0; j < 4; j++) acc[i][j] = zero;

    for (int k0 = 0; k0 < HID; k0 += 32) {
        async16(Ag + k0, Al);
        async16(Ag + k0 + 16 * HID, Al + 512);
        async16(Bg + k0, Bl);
        async16(Bg + k0 + 16 * HID, Bl + 512);
        __syncthreads();
        bf16x8 af[4], bfr[4];
#pragma unroll
        for (int mt = 0; mt < 4; mt++)
            af[mt] = *(const bf16x8*)(Asm + (wm * 64 + mt * 16 + c) * 32 + quad * 8);
#pragma unroll
        for (int nt = 0; nt < 4; nt++)
            bfr[nt] = *(const bf16x8*)(Bsm + (wn * 64 + nt * 16 + c) * 32 + quad * 8);
#pragma unroll
        for (int mt = 0; mt < 4; mt++)
#pragma unroll
            for (int nt = 0; nt < 4; nt++)
                acc[mt][nt] = __builtin_amdgcn_mfma_f32_16x16x32_bf16(af[mt], bfr[nt],
                                                                      acc[mt][nt], 0, 0, 0);
        __syncthreads();
    }

    if (MODE == 2) {
#pragma unroll
        for (int mt = 0; mt < 4; mt++)
#pragma unroll
            for (int nt = 0; nt < 4; nt++)
#pragma unroll
                for (int r = 0; r < 4; r++) {
                    int row = m0 + wm * 64 + mt * 16 + quad * 4 + r;
                    int col = nloc + wn * 64 + nt * 16 + c;
                    Fo[(size_t)row * HID + col] = acc[mt][nt][r];
                }
    } else {
        int nglob0 = n_shift + nloc;
        int mat = nglob0 >> 11;  // block-uniform
        int ncol0 = nglob0 & 2047;
        unsigned short* Cb = (mat == 0) ? Qo : ((mat == 1) ? Ko : Vo);
#pragma unroll
        for (int mt = 0; mt < 4; mt++) {
#pragma unroll
            for (int nt = 0; nt < 4; nt++) {
                int colm = ncol0 + wn * 64 + nt * 16 + c;
                int h = colm >> 7, d = colm & 127;
                if (mat < 2) {
#pragma unroll
                    for (int r = 0; r < 4; r++) {
                        int row = m0 + wm * 64 + mt * 16 + quad * 4 + r;
                        int b = row >> 11, s = row & 2047;
                        Cb[((size_t)(b * NH + h) * S_LEN + s) * HD + d] = f2bf(acc[mt][nt][r]);
                    }
                } else {
                    // V^T: 4 consecutive s per lane -> packed 8B store
                    int row0 = m0 + wm * 64 + mt * 16 + quad * 4;
                    int b = row0 >> 11, s = row0 & 2047;
                    ushort4 o;
                    o.x = f2bf(acc[mt][nt][0]);
                    o.y = f2bf(acc[mt][nt][1]);
                    o.z = f2bf(acc[mt][nt][2]);
                    o.w = f2bf(acc[mt][nt][3]);
                    *(ushort4*)(Cb + ((size_t)(b * NH + h) * HD + d) * S_LEN + s) = o;
                }
            }
        }
    }
}

// ---------------- RoPE in place; Q pre-scaled by log2(e)/sqrt(D) for exp2 softmax ---------
__global__ __launch_bounds__(256) void rope_kernel(unsigned short* __restrict__ Qb,
                                                   unsigned short* __restrict__ Kb,
                                                   const float* __restrict__ cosp,
                                                   const float* __restrict__ sinp) {
    unsigned short* P = blockIdx.y ? Kb : Qb;
    float scq = blockIdx.y ? 1.0f : 0.12751743f;  // 1.4426950409 / sqrt(128)
    int idx = blockIdx.x * 256 + threadIdx.x;  // pair index over B*H*S*64
    int row = idx >> 6, j = idx & 63;
    int s = row & (S_LEN - 1);
    size_t base = (size_t)row * HD;
    float x1 = bf2f(P[base + j]);
    float x2 = bf2f(P[base + j + 64]);
    float c1 = cosp[s * HD + j], s1 = sinp[s * HD + j];
    float c2 = cosp[s * HD + j + 64], s2 = sinp[s * HD + j + 64];
    P[base + j]      = f2bf((x1 * c1 - x2 * s1) * scq);
    P[base + j + 64] = f2bf((x2 * c2 + x1 * s2) * scq);
}

// ---------------- flash attention (no-max online softmax, S^T formulation) ----------------
// Q,K: [b][h][s][d] bf16 (Q pre-scaled incl. log2e).  Vt: [b][h][d][s] bf16.
// Aout: [b*s][h*d] bf16.  Block: 4 waves x 32 q-rows = 128 q-rows. Key chunks of 64.
#define PKS 72  // P row stride in shorts (144B = 9*16: b128-aligned, conflict-free)
__global__ __launch_bounds__(256, 2) void attn_kernel(const unsigned short* __restrict__ Q,
                                                      const unsigned short* __restrict__ Kg,
                                                      const unsigned short* __restrict__ Vt,
                                                      unsigned short* __restrict__ Aout) {
    __shared__ unsigned short Ksm[64 * 128];            // 16 KB, [key][d], XOR-swizzled chunks
    __shared__ unsigned short Vsm[128 * 64];            // 16 KB, [d][key], XOR-swizzled chunks
    __shared__ __align__(16) unsigned short Psm[4 * 2 * 16 * PKS];  // 18 KB
    int bh = blockIdx.y;
    int b = bh >> 4, h = bh & 15;
    int t = threadIdx.x;
    int wave = t >> 6, lane = t & 63;
    int c = lane & 15, quad = lane >> 4;
    int q0 = blockIdx.x * 128 + wave * 32;
    const unsigned short* Qp = Q + (size_t)bh * S_LEN * HD;
    const unsigned short* Kp = Kg + (size_t)bh * S_LEN * HD;
    const unsigned short* Vp = Vt + (size_t)bh * HD * S_LEN;

    // persistent Q fragments: 2 n-tiles (32 q-rows) x 4 k-frags
    bf16x8 qf[2][4];
#pragma unroll
    for (int qn = 0; qn < 2; qn++)
#pragma unroll
        for (int kk = 0; kk < 4; kk++)
            qf[qn][kk] = *(const bf16x8*)(Qp + (size_t)(q0 + qn * 16 + c) * HD + kk * 32 + quad * 8);

    f32x4 zero = {0.f, 0.f, 0.f, 0.f};
    f32x4 o_acc[2][8];
#pragma unroll
    for (int qn = 0; qn < 2; qn++)
#pragma unroll
        for (int nt = 0; nt < 8; nt++) o_acc[qn][nt] = zero;
    float lsum[2] = {0.f, 0.f};

    for (int key0 = 0; key0 < S_LEN; key0 += 64) {
        // stage K[64][128] and Vt[128][64] chunks via async DMA, XOR-swizzled source
#pragma unroll
        for (int j = 0; j < 4; j++) {
            int fc = (wave * 4 + j) * 64 + lane;
            int rK = fc >> 4, cbK = (fc & 15) ^ (rK & 15);
            async16(Kp + (size_t)(key0 + rK) * HD + cbK * 8, Ksm + (wave * 4 + j) * 512);
            int rV = fc >> 3, cbV = (fc & 7) ^ (rV & 7);
            async16(Vp + (size_t)rV * S_LEN + key0 + cbV * 8, Vsm + (wave * 4 + j) * 512);
        }
        __syncthreads();

        // S^T = K * Q^T : M=key (4 tiles), N=qrow (2 tiles), K=d (4 frags)
        f32x4 sacc[4][2];
#pragma unroll
        for (int km = 0; km < 4; km++)
#pragma unroll
            for (int qn = 0; qn < 2; qn++) sacc[km][qn] = zero;
#pragma unroll
        for (int kk = 0; kk < 4; kk++) {
            bf16x8 kfr[4];
#pragma unroll
            for (int km = 0; km < 4; km++)
                kfr[km] = *(const bf16x8*)(Ksm + (km * 16 + c) * HD + (((kk * 4 + quad) ^ c)) * 8);
#pragma unroll
            for (int km = 0; km < 4; km++)
#pragma unroll
                for (int qn = 0; qn < 2; qn++)
                    sacc[km][qn] = __builtin_amdgcn_mfma_f32_16x16x32_bf16(kfr[km], qf[qn][kk],
                                                                           sacc[km][qn], 0, 0, 0);
        }

        // exp2 (scale pre-folded, no max subtraction), row-sum partials, pack P -> LDS
        // C-layout of S^T: lane holds qrow=c, keys km*16 + quad*4 + r (consecutive r!)
#pragma unroll
        for (int qn = 0; qn < 2; qn++) {
#pragma unroll
            for (int km = 0; km < 4; km++) {
                float e0 = exp2_fast(sacc[km][qn][0]);
                float e1 = exp2_fast(sacc[km][qn][1]);
                float e2 = exp2_fast(sacc[km][qn][2]);
                float e3 = exp2_fast(sacc[km][qn][3]);
                lsum[qn] += (e0 + e1) + (e2 + e3);
                uint2 pk;
                pk.x = pkbf(e0, e1);
                pk.y = pkbf(e2, e3);
                *(uint2*)(Psm + ((wave * 2 + qn) * 16 + c) * PKS + km * 16 + quad * 4) = pk;
            }
        }
        // intra-wave LDS write->read ordering (cross-lane): compiler fence + lgkmcnt(0)
        asm volatile("" ::: "memory");
        __builtin_amdgcn_s_waitcnt(0xc07f);  // lgkmcnt(0), vmcnt/expcnt unaffected
        asm volatile("" ::: "memory");

        // O += P * V : A=P [qrow][key], B=Vt [d][key]
#pragma unroll
        for (int kf = 0; kf < 2; kf++) {
            bf16x8 pf[2];
#pragma unroll
            for (int qn = 0; qn < 2; qn++)
                pf[qn] = *(const bf16x8*)(Psm + ((wave * 2 + qn) * 16 + c) * PKS + kf * 32 + quad * 8);
#pragma unroll
            for (int nt = 0; nt < 8; nt++) {
                bf16x8 vf = *(const bf16x8*)(Vsm + (nt * 16 + c) * 64 +
                                             (((kf * 4 + quad) ^ (c & 7))) * 8);
#pragma unroll
                for (int qn = 0; qn < 2; qn++)
                    o_acc[qn][nt] = __builtin_amdgcn_mfma_f32_16x16x32_bf16(pf[qn], vf,
                                                                            o_acc[qn][nt], 0, 0, 0);
            }
        }
        __syncthreads();  // protect Ksm/Vsm before next-iter DMA
    }

    // final: reduce lsum over the 4 quad-lanes (row = c), broadcast to C-layout rows
#pragma unroll
    for (int qn = 0; qn < 2; qn++) {
        lsum[qn] += __shfl_xor(lsum[qn], 16);
        lsum[qn] += __shfl_xor(lsum[qn], 32);
    }
    float inv[2][4];
#pragma unroll
    for (int qn = 0; qn < 2; qn++)
#pragma unroll
        for (int r = 0; r < 4; r++)
            inv[qn][r] = 1.0f / __shfl(lsum[qn], quad * 4 + r);

#pragma unroll
    for (int qn = 0; qn < 2; qn++) {
#pragma unroll
        for (int r = 0; r < 4; r++) {
            int srow = q0 + qn * 16 + quad * 4 + r;
            size_t base = ((size_t)(b * S_LEN + srow)) * HID + h * HD;
#pragma unroll
            for (int nt = 0; nt < 8; nt++)
                Aout[base + nt * 16 + c] = f2bf(o_acc[qn][nt][r] * inv[qn][r]);
        }
    }
}

extern "C" void kernel_launch(void* const* d_in, const int* in_sizes, int n_in,
                              void* d_out, int out_size, void* d_ws, size_t ws_size,
                              hipStream_t stream) {
    const float* hs   = (const float*)d_in[0];
    const float* cosp = (const float*)d_in[1];
    const float* sinp = (const float*)d_in[2];
    const float* Wq   = (const float*)d_in[3];
    const float* Wk   = (const float*)d_in[4];
    const float* Wv   = (const float*)d_in[5];
    const float* Wo   = (const float*)d_in[6];

    char* ws = (char*)d_ws;
    unsigned short* Xb = (unsigned short*)(ws);                      // 16 MB (reused as Aout)
    unsigned short* Qb = (unsigned short*)(ws + (16ull << 20));      // 16 MB
    unsigned short* Kb = (unsigned short*)(ws + (32ull << 20));      // 16 MB
    unsigned short* Vb = (unsigned short*)(ws + (48ull << 20));      // 16 MB
    unsigned short* WT = (unsigned short*)(ws + (64ull << 20));      // 24 MB fused / 8 MB fallback

    const bool fused = ws_size >= (88ull << 20);

    dim3 tb(32, 8);

    cast_f32_bf16<<<8192, 256, 0, stream>>>(hs, Xb, NROWS * HID);

    if (fused) {
        transpose_cast<<<dim3(64, 64, 3), tb, 0, stream>>>(Wq, Wk, Wv, WT);
        gemm_bt<0><<<dim3(48, 32), 256, 0, stream>>>(Xb, WT, Qb, Kb, Vb, nullptr, 0);
    } else {
        transpose_cast<<<dim3(64, 64, 1), tb, 0, stream>>>(Wq, Wq, Wq, WT);
        gemm_bt<0><<<dim3(16, 32), 256, 0, stream>>>(Xb, WT, Qb, Kb, Vb, nullptr, 0);
        transpose_cast<<<dim3(64, 64, 1), tb, 0, stream>>>(Wk, Wk, Wk, WT);
        gemm_bt<0><<<dim3(16, 32), 256, 0, stream>>>(Xb, WT, Qb, Kb, Vb, nullptr, 2048);
        transpose_cast<<<dim3(64, 64, 1), tb, 0, stream>>>(Wv, Wv, Wv, WT);
        gemm_bt<0><<<dim3(16, 32), 256, 0, stream>>>(Xb, WT, Qb, Kb, Vb, nullptr, 4096);
    }

    rope_kernel<<<dim3(16384, 2), 256, 0, stream>>>(Qb, Kb, cosp, sinp);

    attn_kernel<<<dim3(16, 32), 256, 0, stream>>>(Qb, Kb, Vb, Xb /*Aout*/);

    transpose_cast<<<dim3(64, 64, 1), tb, 0, stream>>>(Wo, Wo, Wo, WT);
    gemm_bt<2><<<dim3(16, 32), 256, 0, stream>>>(Xb, WT, nullptr, nullptr, nullptr,
                                                 (float*)d_out, 0);
}

// Round 4
// 417.087 us; speedup vs baseline: 1.5171x; 1.0136x over previous
//
#include <hip/hip_runtime.h>

typedef short bf16x8 __attribute__((ext_vector_type(8)));
typedef float f32x4 __attribute__((ext_vector_type(4)));

#define HID   2048
#define S_LEN 2048
#define NH    16
#define HD    128
#define BATCH 2
#define NROWS (BATCH * S_LEN)  // 4096

__device__ __forceinline__ float bf2f(unsigned short u) {
    union { unsigned int i; float f; } v;
    v.i = ((unsigned int)u) << 16;
    return v.f;
}
__device__ __forceinline__ unsigned short f2bf(float f) {
    union { float f; unsigned int i; } v;
    v.f = f;
    unsigned int u = v.i;
    return (unsigned short)((u + 0x7fffu + ((u >> 16) & 1u)) >> 16);
}

// packed f32x2 -> bf16x2 (RNE). Prefer HW v_cvt_pk_bf16_f32 on gfx950.
__device__ __forceinline__ unsigned int pkbf(float a, float b) {
#if defined(__has_builtin) && __has_builtin(__builtin_amdgcn_cvt_pk_bf16_f32)
    typedef __bf16 bf2_t __attribute__((ext_vector_type(2)));
    bf2_t v = __builtin_amdgcn_cvt_pk_bf16_f32(a, b);
    unsigned int u;
    __builtin_memcpy(&u, &v, 4);
    return u;
#else
    return (unsigned int)f2bf(a) | ((unsigned int)f2bf(b) << 16);
#endif
}

__device__ __forceinline__ float exp2_fast(float x) {
#if defined(__has_builtin) && __has_builtin(__builtin_amdgcn_exp2f)
    return __builtin_amdgcn_exp2f(x);
#else
    return __expf(x * 0.6931471805599453f);
#endif
}

// async global->LDS, 16B per lane. LDS dest = wave-uniform base + lane*16B.
__device__ __forceinline__ void async16(const unsigned short* g, unsigned short* l) {
    __builtin_amdgcn_global_load_lds(
        (const __attribute__((address_space(1))) unsigned int*)g,
        (__attribute__((address_space(3))) unsigned int*)l, 16, 0, 0);
}

// ---------------- cast fp32 -> bf16 ----------------
__global__ __launch_bounds__(256) void cast_f32_bf16(const float* __restrict__ x,
                                                     unsigned short* __restrict__ y, int n) {
    int i = (blockIdx.x * 256 + threadIdx.x) * 4;
    if (i < n) {
        float4 v = *(const float4*)(x + i);
        uint2 o;
        o.x = pkbf(v.x, v.y);
        o.y = pkbf(v.z, v.w);
        *(uint2*)(y + i) = o;
    }
}

// ---------------- merge: out = a + b (fp32, split-K reduction) ----------------
__global__ __launch_bounds__(256) void merge_add(const float* __restrict__ a,
                                                 const float* __restrict__ b,
                                                 float* __restrict__ o, int n) {
    int i = (blockIdx.x * 256 + threadIdx.x) * 4;
    if (i < n) {
        float4 x = *(const float4*)(a + i);
        float4 y = *(const float4*)(b + i);
        x.x += y.x; x.y += y.y; x.z += y.z; x.w += y.w;
        *(float4*)(o + i) = x;
    }
}

// ---------------- transpose + cast: W[k][o] fp32 -> WT[z][o][k] bf16 ----------------
__global__ __launch_bounds__(256) void transpose_cast(const float* __restrict__ Wa,
                                                      const float* __restrict__ Wb,
                                                      const float* __restrict__ Wc,
                                                      unsigned short* __restrict__ WT) {
    __shared__ float tile[32][33];
    int tx = threadIdx.x, ty = threadIdx.y;  // 32 x 8
    int bx = blockIdx.x, by = blockIdx.y, z = blockIdx.z;
    const float* W = (z == 0) ? Wa : ((z == 1) ? Wb : Wc);
    unsigned short* dst = WT + (size_t)z * HID * HID;
#pragma unroll
    for (int i = 0; i < 4; i++)
        tile[ty + i * 8][tx] = W[(size_t)(by * 32 + ty + i * 8) * HID + bx * 32 + tx];
    __syncthreads();
#pragma unroll
    for (int i = 0; i < 4; i++)
        dst[(size_t)(bx * 32 + ty + i * 8) * HID + by * 32 + tx] = f2bf(tile[tx][ty + i * 8]);
}

// ---------------- bf16 GEMM, BK=64 XOR-swizzled staging ----------------
// C[m][nglob] = sum_k A[m][k] * Bt[nloc][k]
// MODE 0: route by global col: mat 0 -> Qo [b][h][s][d], mat 1 -> Ko same, mat 2 -> Vo [b][h][d][s]
// MODE 2: write fp32 to Fo + blockIdx.z*NROWS*HID, K-range = blockIdx.z*kiters*64 .. +kiters*64
template <int MODE>
__global__ __launch_bounds__(256, 2) void gemm_bt(const unsigned short* __restrict__ A,
                                                  const unsigned short* __restrict__ Bt,
                                                  unsigned short* __restrict__ Qo,
                                                  unsigned short* __restrict__ Ko,
                                                  unsigned short* __restrict__ Vo,
                                                  float* __restrict__ Fo,
                                                  int n_shift, int kiters) {
    __shared__ unsigned short Asm[128 * 64];  // 16 KB, row stride 128B, XOR-swizzled cols
    __shared__ unsigned short Bsm[128 * 64];  // 16 KB
    int t = threadIdx.x;
    int wave = t >> 6, lane = t & 63;
    int wm = wave >> 1, wn = wave & 1;
    int c = lane & 15, quad = lane >> 4;
    int m0 = blockIdx.y * 128, nloc = blockIdx.x * 128;

    // staging: wave w stages rows w*32..+31. issue j covers rows w*32+j*8..+7.
    // lane -> row_in_8 = lane/8, swizzled col-block cb = (lane&7) ^ ((lane/8)&7)  (16B units)
    int lr = lane >> 3;
    int cb = (lane & 7) ^ (lr & 7);
    size_t kbase = (size_t)blockIdx.z * kiters * 64;
    const unsigned short* Ag = A + (size_t)(m0 + wave * 32 + lr) * HID + kbase + cb * 8;
    const unsigned short* Bg = Bt + (size_t)(nloc + wave * 32 + lr) * HID + kbase + cb * 8;
    unsigned short* Al = Asm + wave * 2048;  // 32 rows * 64 shorts
    unsigned short* Bl = Bsm + wave * 2048;

    f32x4 zero = {0.f, 0.f, 0.f, 0.f};
    f32x4 acc[4][4];
#pragma unroll
    for (int i = 0; i < 4; i++)
#pragma unroll
        for (int j = 0; j < 4; j++) acc[i][j] = zero;

    for (int it = 0; it < kiters; it++) {
        int k0 = it * 64;
#pragma unroll
        for (int j = 0; j < 4; j++) {
            async16(Ag + k0 + j * 8 * HID, Al + j * 512);
            async16(Bg + k0 + j * 8 * HID, Bl + j * 512);
        }
        __syncthreads();
#pragma unroll
        for (int kk = 0; kk < 2; kk++) {
            bf16x8 af[4], bfr[4];
#pragma unroll
            for (int mt = 0; mt < 4; mt++)
                af[mt] = *(const bf16x8*)(Asm + (wm * 64 + mt * 16 + c) * 64 +
                                          (((kk * 4 + quad) ^ (c & 7)) * 8));
#pragma unroll
            for (int nt = 0; nt < 4; nt++)
                bfr[nt] = *(const bf16x8*)(Bsm + (wn * 64 + nt * 16 + c) * 64 +
                                           (((kk * 4 + quad) ^ (c & 7)) * 8));
#pragma unroll
            for (int mt = 0; mt < 4; mt++)
#pragma unroll
                for (int nt = 0; nt < 4; nt++)
                    acc[mt][nt] = __builtin_amdgcn_mfma_f32_16x16x32_bf16(af[mt], bfr[nt],
                                                                          acc[mt][nt], 0, 0, 0);
        }
        __syncthreads();
    }

    if (MODE == 2) {
        float* Foz = Fo + (size_t)blockIdx.z * NROWS * HID;
#pragma unroll
        for (int mt = 0; mt < 4; mt++)
#pragma unroll
            for (int nt = 0; nt < 4; nt++)
#pragma unroll
                for (int r = 0; r < 4; r++) {
                    int row = m0 + wm * 64 + mt * 16 + quad * 4 + r;
                    int col = nloc + wn * 64 + nt * 16 + c;
                    Foz[(size_t)row * HID + col] = acc[mt][nt][r];
                }
    } else {
        int nglob0 = n_shift + nloc;
        int mat = nglob0 >> 11;  // block-uniform
        int ncol0 = nglob0 & 2047;
        unsigned short* Cb = (mat == 0) ? Qo : ((mat == 1) ? Ko : Vo);
#pragma unroll
        for (int mt = 0; mt < 4; mt++) {
#pragma unroll
            for (int nt = 0; nt < 4; nt++) {
                int colm = ncol0 + wn * 64 + nt * 16 + c;
                int h = colm >> 7, d = colm & 127;
                if (mat < 2) {
#pragma unroll
                    for (int r = 0; r < 4; r++) {
                        int row = m0 + wm * 64 + mt * 16 + quad * 4 + r;
                        int b = row >> 11, s = row & 2047;
                        Cb[((size_t)(b * NH + h) * S_LEN + s) * HD + d] = f2bf(acc[mt][nt][r]);
                    }
                } else {
                    // V^T: 4 consecutive s per lane -> packed 8B store
                    int row0 = m0 + wm * 64 + mt * 16 + quad * 4;
                    int b = row0 >> 11, s = row0 & 2047;
                    ushort4 o;
                    o.x = f2bf(acc[mt][nt][0]);
                    o.y = f2bf(acc[mt][nt][1]);
                    o.z = f2bf(acc[mt][nt][2]);
                    o.w = f2bf(acc[mt][nt][3]);
                    *(ushort4*)(Cb + ((size_t)(b * NH + h) * HD + d) * S_LEN + s) = o;
                }
            }
        }
    }
}

// ---------------- RoPE in place; Q pre-scaled by log2(e)/sqrt(D) for exp2 softmax ---------
__global__ __launch_bounds__(256) void rope_kernel(unsigned short* __restrict__ Qb,
                                                   unsigned short* __restrict__ Kb,
                                                   const float* __restrict__ cosp,
                                                   const float* __restrict__ sinp) {
    unsigned short* P = blockIdx.y ? Kb : Qb;
    float scq = blockIdx.y ? 1.0f : 0.12751743f;  // 1.4426950409 / sqrt(128)
    int idx = blockIdx.x * 256 + threadIdx.x;  // pair index over B*H*S*64
    int row = idx >> 6, j = idx & 63;
    int s = row & (S_LEN - 1);
    size_t base = (size_t)row * HD;
    float x1 = bf2f(P[base + j]);
    float x2 = bf2f(P[base + j + 64]);
    float c1 = cosp[s * HD + j], s1 = sinp[s * HD + j];
    float c2 = cosp[s * HD + j + 64], s2 = sinp[s * HD + j + 64];
    P[base + j]      = f2bf((x1 * c1 - x2 * s1) * scq);
    P[base + j + 64] = f2bf((x2 * c2 + x1 * s2) * scq);
}

// ---------------- flash attention (no-max online softmax, S^T formulation) ----------------
// Q,K: [b][h][s][d] bf16 (Q pre-scaled incl. log2e).  Vt: [b][h][d][s] bf16.
// Aout: [b*s][h*d] bf16.  Block: 4 waves x 32 q-rows = 128 q-rows. Key chunks of 64.
#define PKS 72  // P row stride in shorts (144B = 9*16: b128-aligned, conflict-free)
__global__ __launch_bounds__(256, 2) void attn_kernel(const unsigned short* __restrict__ Q,
                                                      const unsigned short* __restrict__ Kg,
                                                      const unsigned short* __restrict__ Vt,
                                                      unsigned short* __restrict__ Aout) {
    __shared__ unsigned short Ksm[64 * 128];            // 16 KB, [key][d], XOR-swizzled chunks
    __shared__ unsigned short Vsm[128 * 64];            // 16 KB, [d][key], XOR-swizzled chunks
    __shared__ __align__(16) unsigned short Psm[4 * 2 * 16 * PKS];  // 18 KB
    int bh = blockIdx.y;
    int b = bh >> 4, h = bh & 15;
    int t = threadIdx.x;
    int wave = t >> 6, lane = t & 63;
    int c = lane & 15, quad = lane >> 4;
    int q0 = blockIdx.x * 128 + wave * 32;
    const unsigned short* Qp = Q + (size_t)bh * S_LEN * HD;
    const unsigned short* Kp = Kg + (size_t)bh * S_LEN * HD;
    const unsigned short* Vp = Vt + (size_t)bh * HD * S_LEN;

    // persistent Q fragments: 2 n-tiles (32 q-rows) x 4 k-frags
    bf16x8 qf[2][4];
#pragma unroll
    for (int qn = 0; qn < 2; qn++)
#pragma unroll
        for (int kk = 0; kk < 4; kk++)
            qf[qn][kk] = *(const bf16x8*)(Qp + (size_t)(q0 + qn * 16 + c) * HD + kk * 32 + quad * 8);

    f32x4 zero = {0.f, 0.f, 0.f, 0.f};
    f32x4 o_acc[2][8];
#pragma unroll
    for (int qn = 0; qn < 2; qn++)
#pragma unroll
        for (int nt = 0; nt < 8; nt++) o_acc[qn][nt] = zero;
    float lsum[2] = {0.f, 0.f};

    for (int key0 = 0; key0 < S_LEN; key0 += 64) {
        // stage K[64][128] and Vt[128][64] chunks via async DMA, XOR-swizzled source
#pragma unroll
        for (int j = 0; j < 4; j++) {
            int fc = (wave * 4 + j) * 64 + lane;
            int rK = fc >> 4, cbK = (fc & 15) ^ (rK & 15);
            async16(Kp + (size_t)(key0 + rK) * HD + cbK * 8, Ksm + (wave * 4 + j) * 512);
            int rV = fc >> 3, cbV = (fc & 7) ^ (rV & 7);
            async16(Vp + (size_t)rV * S_LEN + key0 + cbV * 8, Vsm + (wave * 4 + j) * 512);
        }
        __syncthreads();

        // S^T = K * Q^T : M=key (4 tiles), N=qrow (2 tiles), K=d (4 frags)
        f32x4 sacc[4][2];
#pragma unroll
        for (int km = 0; km < 4; km++)
#pragma unroll
            for (int qn = 0; qn < 2; qn++) sacc[km][qn] = zero;
#pragma unroll
        for (int kk = 0; kk < 4; kk++) {
            bf16x8 kfr[4];
#pragma unroll
            for (int km = 0; km < 4; km++)
                kfr[km] = *(const bf16x8*)(Ksm + (km * 16 + c) * HD + (((kk * 4 + quad) ^ c)) * 8);
#pragma unroll
            for (int km = 0; km < 4; km++)
#pragma unroll
                for (int qn = 0; qn < 2; qn++)
                    sacc[km][qn] = __builtin_amdgcn_mfma_f32_16x16x32_bf16(kfr[km], qf[qn][kk],
                                                                           sacc[km][qn], 0, 0, 0);
        }

        // exp2 (scale pre-folded, no max subtraction), row-sum partials, pack P -> LDS
        // C-layout of S^T: lane holds qrow=c, keys km*16 + quad*4 + r (consecutive r!)
#pragma unroll
        for (int qn = 0; qn < 2; qn++) {
#pragma unroll
            for (int km = 0; km < 4; km++) {
                float e0 = exp2_fast(sacc[km][qn][0]);
                float e1 = exp2_fast(sacc[km][qn][1]);
                float e2 = exp2_fast(sacc[km][qn][2]);
                float e3 = exp2_fast(sacc[km][qn][3]);
                lsum[qn] += (e0 + e1) + (e2 + e3);
                uint2 pk;
                pk.x = pkbf(e0, e1);
                pk.y = pkbf(e2, e3);
                *(uint2*)(Psm + ((wave * 2 + qn) * 16 + c) * PKS + km * 16 + quad * 4) = pk;
            }
        }
        // intra-wave LDS write->read ordering (cross-lane): compiler fence + lgkmcnt(0)
        asm volatile("" ::: "memory");
        __builtin_amdgcn_s_waitcnt(0xc07f);  // lgkmcnt(0), vmcnt/expcnt unaffected
        asm volatile("" ::: "memory");

        // O += P * V : A=P [qrow][key], B=Vt [d][key]
#pragma unroll
        for (int kf = 0; kf < 2; kf++) {
            bf16x8 pf[2];
#pragma unroll
            for (int qn = 0; qn < 2; qn++)
                pf[qn] = *(const bf16x8*)(Psm + ((wave * 2 + qn) * 16 + c) * PKS + kf * 32 + quad * 8);
#pragma unroll
            for (int nt = 0; nt < 8; nt++) {
                bf16x8 vf = *(const bf16x8*)(Vsm + (nt * 16 + c) * 64 +
                                             (((kf * 4 + quad) ^ (c & 7))) * 8);
#pragma unroll
                for (int qn = 0; qn < 2; qn++)
                    o_acc[qn][nt] = __builtin_amdgcn_mfma_f32_16x16x32_bf16(pf[qn], vf,
                                                                            o_acc[qn][nt], 0, 0, 0);
            }
        }
        __syncthreads();  // protect Ksm/Vsm before next-iter DMA
    }

    // final: reduce lsum over the 4 quad-lanes (row = c), broadcast to C-layout rows
#pragma unroll
    for (int qn = 0; qn < 2; qn++) {
        lsum[qn] += __shfl_xor(lsum[qn], 16);
        lsum[qn] += __shfl_xor(lsum[qn], 32);
    }
    float inv[2][4];
#pragma unroll
    for (int qn = 0; qn < 2; qn++)
#pragma unroll
        for (int r = 0; r < 4; r++)
            inv[qn][r] = 1.0f / __shfl(lsum[qn], quad * 4 + r);

#pragma unroll
    for (int qn = 0; qn < 2; qn++) {
#pragma unroll
        for (int r = 0; r < 4; r++) {
            int srow = q0 + qn * 16 + quad * 4 + r;
            size_t base = ((size_t)(b * S_LEN + srow)) * HID + h * HD;
#pragma unroll
            for (int nt = 0; nt < 8; nt++)
                Aout[base + nt * 16 + c] = f2bf(o_acc[qn][nt][r] * inv[qn][r]);
        }
    }
}

extern "C" void kernel_launch(void* const* d_in, const int* in_sizes, int n_in,
                              void* d_out, int out_size, void* d_ws, size_t ws_size,
                              hipStream_t stream) {
    const float* hs   = (const float*)d_in[0];
    const float* cosp = (const float*)d_in[1];
    const float* sinp = (const float*)d_in[2];
    const float* Wq   = (const float*)d_in[3];
    const float* Wk   = (const float*)d_in[4];
    const float* Wv   = (const float*)d_in[5];
    const float* Wo   = (const float*)d_in[6];

    char* ws = (char*)d_ws;
    unsigned short* Xb = (unsigned short*)(ws);                      // 0-16 MB (reused as Aout)
    unsigned short* Qb = (unsigned short*)(ws + (16ull << 20));      // 16-32
    unsigned short* Kb = (unsigned short*)(ws + (32ull << 20));      // 32-48
    unsigned short* Vb = (unsigned short*)(ws + (48ull << 20));      // 48-64
    unsigned short* WT = (unsigned short*)(ws + (64ull << 20));      // 64-88 fused / 64-72 single

    const bool fused = ws_size >= (88ull << 20);

    dim3 tb(32, 8);

    cast_f32_bf16<<<8192, 256, 0, stream>>>(hs, Xb, NROWS * HID);

    if (fused) {
        transpose_cast<<<dim3(64, 64, 3), tb, 0, stream>>>(Wq, Wk, Wv, WT);
        gemm_bt<0><<<dim3(48, 32, 1), 256, 0, stream>>>(Xb, WT, Qb, Kb, Vb, nullptr, 0, 32);
    } else {
        transpose_cast<<<dim3(64, 64, 1), tb, 0, stream>>>(Wq, Wq, Wq, WT);
        gemm_bt<0><<<dim3(16, 32, 1), 256, 0, stream>>>(Xb, WT, Qb, Kb, Vb, nullptr, 0, 32);
        transpose_cast<<<dim3(64, 64, 1), tb, 0, stream>>>(Wk, Wk, Wk, WT);
        gemm_bt<0><<<dim3(16, 32, 1), 256, 0, stream>>>(Xb, WT, Qb, Kb, Vb, nullptr, 2048, 32);
        transpose_cast<<<dim3(64, 64, 1), tb, 0, stream>>>(Wv, Wv, Wv, WT);
        gemm_bt<0><<<dim3(16, 32, 1), 256, 0, stream>>>(Xb, WT, Qb, Kb, Vb, nullptr, 4096, 32);
    }

    rope_kernel<<<dim3(16384, 2), 256, 0, stream>>>(Qb, Kb, cosp, sinp);

    attn_kernel<<<dim3(16, 32), 256, 0, stream>>>(Qb, Kb, Vb, Xb /*Aout*/);

    if (fused) {
        // Qb/Kb/Vb/WT are dead now. WoT at 16-24 MB; split-K partials at 24-56 / 56-88 MB.
        unsigned short* WoT = (unsigned short*)(ws + (16ull << 20));
        float* Pf = (float*)(ws + (24ull << 20));
        transpose_cast<<<dim3(64, 64, 1), tb, 0, stream>>>(Wo, Wo, Wo, WoT);
        gemm_bt<2><<<dim3(16, 32, 2), 256, 0, stream>>>(Xb, WoT, nullptr, nullptr, nullptr,
                                                        Pf, 0, 16);
        merge_add<<<8192, 256, 0, stream>>>(Pf, Pf + (size_t)NROWS * HID, (float*)d_out,
                                            NROWS * HID);
    } else {
        transpose_cast<<<dim3(64, 64, 1), tb, 0, stream>>>(Wo, Wo, Wo, WT);
        gemm_bt<2><<<dim3(16, 32, 1), 256, 0, stream>>>(Xb, WT, nullptr, nullptr, nullptr,
                                                        (float*)d_out, 0, 32);
    }
}

// Round 5
// 396.654 us; speedup vs baseline: 1.5952x; 1.0515x over previous
//
#include <hip/hip_runtime.h>

typedef short bf16x8 __attribute__((ext_vector_type(8)));
typedef float f32x4 __attribute__((ext_vector_type(4)));

#define HID   2048
#define S_LEN 2048
#define NH    16
#define HD    128
#define BATCH 2
#define NROWS (BATCH * S_LEN)  // 4096

__device__ __forceinline__ float bf2f(unsigned short u) {
    union { unsigned int i; float f; } v;
    v.i = ((unsigned int)u) << 16;
    return v.f;
}
__device__ __forceinline__ unsigned short f2bf(float f) {
    union { float f; unsigned int i; } v;
    v.f = f;
    unsigned int u = v.i;
    return (unsigned short)((u + 0x7fffu + ((u >> 16) & 1u)) >> 16);
}

// packed f32x2 -> bf16x2 (RNE). Prefer HW v_cvt_pk_bf16_f32 on gfx950.
__device__ __forceinline__ unsigned int pkbf(float a, float b) {
#if defined(__has_builtin) && __has_builtin(__builtin_amdgcn_cvt_pk_bf16_f32)
    typedef __bf16 bf2_t __attribute__((ext_vector_type(2)));
    bf2_t v = __builtin_amdgcn_cvt_pk_bf16_f32(a, b);
    unsigned int u;
    __builtin_memcpy(&u, &v, 4);
    return u;
#else
    return (unsigned int)f2bf(a) | ((unsigned int)f2bf(b) << 16);
#endif
}

__device__ __forceinline__ float exp2_fast(float x) {
#if defined(__has_builtin) && __has_builtin(__builtin_amdgcn_exp2f)
    return __builtin_amdgcn_exp2f(x);
#else
    return __expf(x * 0.6931471805599453f);
#endif
}

// async global->LDS, 16B per lane. LDS dest = wave-uniform base + lane*16B.
__device__ __forceinline__ void async16(const unsigned short* g, unsigned short* l) {
    __builtin_amdgcn_global_load_lds(
        (const __attribute__((address_space(1))) unsigned int*)g,
        (__attribute__((address_space(3))) unsigned int*)l, 16, 0, 0);
}

// ---------------- prep: z<3 -> transpose+cast W_z; z==3 -> cast hs -> bf16 ----------------
__global__ __launch_bounds__(256) void prep(const float* __restrict__ hs,
                                            const float* __restrict__ Wa,
                                            const float* __restrict__ Wb,
                                            const float* __restrict__ Wc,
                                            unsigned short* __restrict__ Xb,
                                            unsigned short* __restrict__ WT) {
    int z = blockIdx.z;
    int t = threadIdx.x;
    if (z == 3) {
        // cast: 4096 blocks * 256 threads * 8 floats = 8.39M = NROWS*HID exactly
        size_t idx = (((size_t)blockIdx.y * 64 + blockIdx.x) * 256 + t) * 8;
        float4 v0 = *(const float4*)(hs + idx);
        float4 v1 = *(const float4*)(hs + idx + 4);
        uint4 o;
        o.x = pkbf(v0.x, v0.y);
        o.y = pkbf(v0.z, v0.w);
        o.z = pkbf(v1.x, v1.y);
        o.w = pkbf(v1.z, v1.w);
        *(uint4*)(Xb + idx) = o;
        return;
    }
    __shared__ float tile[32][33];
    int tx = t & 31, ty = t >> 5;  // 32 x 8
    int bx = blockIdx.x, by = blockIdx.y;
    const float* W = (z == 0) ? Wa : ((z == 1) ? Wb : Wc);
    unsigned short* dst = WT + (size_t)z * HID * HID;
#pragma unroll
    for (int i = 0; i < 4; i++)
        tile[ty + i * 8][tx] = W[(size_t)(by * 32 + ty + i * 8) * HID + bx * 32 + tx];
    __syncthreads();
#pragma unroll
    for (int i = 0; i < 4; i++)
        dst[(size_t)(bx * 32 + ty + i * 8) * HID + by * 32 + tx] = f2bf(tile[tx][ty + i * 8]);
}

// ---------------- standalone transpose + cast (used for Wo) ----------------
__global__ __launch_bounds__(256) void transpose_cast(const float* __restrict__ W,
                                                      unsigned short* __restrict__ WT) {
    __shared__ float tile[32][33];
    int t = threadIdx.x;
    int tx = t & 31, ty = t >> 5;
    int bx = blockIdx.x, by = blockIdx.y;
#pragma unroll
    for (int i = 0; i < 4; i++)
        tile[ty + i * 8][tx] = W[(size_t)(by * 32 + ty + i * 8) * HID + bx * 32 + tx];
    __syncthreads();
#pragma unroll
    for (int i = 0; i < 4; i++)
        WT[(size_t)(bx * 32 + ty + i * 8) * HID + by * 32 + tx] = f2bf(tile[tx][ty + i * 8]);
}

// ---------------- bf16 GEMM, BK=64 XOR-swizzled staging, fused-RoPE epilogue ----------------
// C[m][nglob] = sum_k A[m][k] * Bt[nloc][k]
// MODE 0: mat = nglob>>11: 0 -> Qo (rope, *log2e/sqrt(D)), 1 -> Ko (rope), both [b][h][s][d];
//         2 -> Vo [b][h][d][s] (transposed, packed stores)
// MODE 2: write fp32 to Fo[row][col]
template <int MODE>
__global__ __launch_bounds__(256, 2) void gemm_bt(const unsigned short* __restrict__ A,
                                                  const unsigned short* __restrict__ Bt,
                                                  unsigned short* __restrict__ Qo,
                                                  unsigned short* __restrict__ Ko,
                                                  unsigned short* __restrict__ Vo,
                                                  float* __restrict__ Fo,
                                                  const float* __restrict__ cosp,
                                                  const float* __restrict__ sinp,
                                                  int n_shift) {
    __shared__ unsigned short SM[16384];       // 32 KB: Asm(16K) + Bsm(16K); reused for rope swap
    unsigned short* Asm = SM;                  // 128 rows x 64 shorts, XOR-swizzled cols
    unsigned short* Bsm = SM + 8192;
    int t = threadIdx.x;
    int wave = t >> 6, lane = t & 63;
    int wm = wave >> 1, wn = wave & 1;
    int c = lane & 15, quad = lane >> 4;
    int m0 = blockIdx.y * 128, nloc = blockIdx.x * 128;

    // staging: wave w stages rows w*32..+31. issue j covers rows w*32+j*8..+7.
    // lane -> row_in_8 = lane/8, swizzled col-block cb = (lane&7) ^ ((lane/8)&7)  (16B units)
    int lr = lane >> 3;
    int cb = (lane & 7) ^ (lr & 7);
    const unsigned short* Ag = A + (size_t)(m0 + wave * 32 + lr) * HID + cb * 8;
    const unsigned short* Bg = Bt + (size_t)(nloc + wave * 32 + lr) * HID + cb * 8;
    unsigned short* Al = Asm + wave * 2048;  // 32 rows * 64 shorts
    unsigned short* Bl = Bsm + wave * 2048;

    f32x4 zero = {0.f, 0.f, 0.f, 0.f};
    f32x4 acc[4][4];
#pragma unroll
    for (int i = 0; i < 4; i++)
#pragma unroll
        for (int j = 0; j < 4; j++) acc[i][j] = zero;

    for (int it = 0; it < 32; it++) {
        int k0 = it * 64;
#pragma unroll
        for (int j = 0; j < 4; j++) {
            async16(Ag + k0 + j * 8 * HID, Al + j * 512);
            async16(Bg + k0 + j * 8 * HID, Bl + j * 512);
        }
        __syncthreads();
#pragma unroll
        for (int kk = 0; kk < 2; kk++) {
            bf16x8 af[4], bfr[4];
#pragma unroll
            for (int mt = 0; mt < 4; mt++)
                af[mt] = *(const bf16x8*)(Asm + (wm * 64 + mt * 16 + c) * 64 +
                                          (((kk * 4 + quad) ^ (c & 7)) * 8));
#pragma unroll
            for (int nt = 0; nt < 4; nt++)
                bfr[nt] = *(const bf16x8*)(Bsm + (wn * 64 + nt * 16 + c) * 64 +
                                           (((kk * 4 + quad) ^ (c & 7)) * 8));
#pragma unroll
            for (int mt = 0; mt < 4; mt++)
#pragma unroll
                for (int nt = 0; nt < 4; nt++)
                    acc[mt][nt] = __builtin_amdgcn_mfma_f32_16x16x32_bf16(af[mt], bfr[nt],
                                                                          acc[mt][nt], 0, 0, 0);
        }
        __syncthreads();
    }

    if (MODE == 2) {
#pragma unroll
        for (int mt = 0; mt < 4; mt++)
#pragma unroll
            for (int nt = 0; nt < 4; nt++)
#pragma unroll
                for (int r = 0; r < 4; r++) {
                    int row = m0 + wm * 64 + mt * 16 + quad * 4 + r;
                    int col = nloc + wn * 64 + nt * 16 + c;
                    Fo[(size_t)row * HID + col] = acc[mt][nt][r];
                }
    } else {
        int nglob0 = n_shift + nloc;
        int mat = nglob0 >> 11;         // block-uniform
        int h = (nglob0 & 2047) >> 7;   // block covers exactly one head (128 cols)
        if (mat == 2) {
            // V^T: 4 consecutive s per lane -> packed 8B store
#pragma unroll
            for (int mt = 0; mt < 4; mt++)
#pragma unroll
                for (int nt = 0; nt < 4; nt++) {
                    int d = wn * 64 + nt * 16 + c;
                    int row0 = m0 + wm * 64 + mt * 16 + quad * 4;
                    int b = row0 >> 11, s = row0 & 2047;
                    ushort4 o;
                    o.x = f2bf(acc[mt][nt][0]);
                    o.y = f2bf(acc[mt][nt][1]);
                    o.z = f2bf(acc[mt][nt][2]);
                    o.w = f2bf(acc[mt][nt][3]);
                    *(ushort4*)(Vo + ((size_t)(b * NH + h) * HD + d) * S_LEN + s) = o;
                }
        } else {
            // Q/K with fused RoPE. Pair (d, d+64) lives in the wn-partner wave at the same
            // lane & (mt,nt,r) slot. Swap via LDS (SM is dead; layout is lane-consecutive
            // -> conflict-free). Then: wn==0: own*cos - part*sin ; wn==1: own*cos + part*sin.
            unsigned short* Cb = (mat == 0) ? Qo : Ko;
            float scl = (mat == 0) ? 0.12751743f : 1.0f;  // log2(e)/sqrt(128) folded into Q
            __syncthreads();  // ensure all waves done with main-loop SM reads (redundant but safe)
#pragma unroll
            for (int mt = 0; mt < 4; mt++)
#pragma unroll
                for (int nt = 0; nt < 4; nt++) {
                    ushort4 o;
                    o.x = f2bf(acc[mt][nt][0]);
                    o.y = f2bf(acc[mt][nt][1]);
                    o.z = f2bf(acc[mt][nt][2]);
                    o.w = f2bf(acc[mt][nt][3]);
                    *(ushort4*)(SM + (mt * 4 + nt) * 1024 + t * 4) = o;
                }
            __syncthreads();
            int partner = (wm * 2 + (wn ^ 1)) * 64 + lane;
            float sgn = wn ? 1.0f : -1.0f;
#pragma unroll
            for (int mt = 0; mt < 4; mt++) {
#pragma unroll
                for (int nt = 0; nt < 4; nt++) {
                    ushort4 pv = *(const ushort4*)(SM + (mt * 4 + nt) * 1024 + partner * 4);
                    float part[4] = {bf2f(pv.x), bf2f(pv.y), bf2f(pv.z), bf2f(pv.w)};
                    int col = wn * 64 + nt * 16 + c;
#pragma unroll
                    for (int r = 0; r < 4; r++) {
                        int row = m0 + wm * 64 + mt * 16 + quad * 4 + r;
                        int b = row >> 11, s = row & 2047;
                        float cv = cosp[s * HD + col], sv = sinp[s * HD + col];
                        float out = (acc[mt][nt][r] * cv + sgn * part[r] * sv) * scl;
                        Cb[((size_t)(b * NH + h) * S_LEN + s) * HD + col] = f2bf(out);
                    }
                }
            }
        }
    }
}

// ---------------- flash attention (no-max online softmax, S^T formulation) ----------------
// Q,K: [b][h][s][d] bf16 (Q pre-scaled incl. log2e).  Vt: [b][h][d][s] bf16.
// Aout: [b*s][h*d] bf16.  Block: 4 waves x 32 q-rows = 128 q-rows. Key chunks of 64.
#define PKS 72  // P row stride in shorts (144B = 9*16: b128-aligned, conflict-free)
__global__ __launch_bounds__(256, 2) void attn_kernel(const unsigned short* __restrict__ Q,
                                                      const unsigned short* __restrict__ Kg,
                                                      const unsigned short* __restrict__ Vt,
                                                      unsigned short* __restrict__ Aout) {
    __shared__ unsigned short Ksm[64 * 128];            // 16 KB, [key][d], XOR-swizzled chunks
    __shared__ unsigned short Vsm[128 * 64];            // 16 KB, [d][key], XOR-swizzled chunks
    __shared__ __align__(16) unsigned short Psm[4 * 2 * 16 * PKS];  // 18 KB
    int bh = blockIdx.y;
    int b = bh >> 4, h = bh & 15;
    int t = threadIdx.x;
    int wave = t >> 6, lane = t & 63;
    int c = lane & 15, quad = lane >> 4;
    int q0 = blockIdx.x * 128 + wave * 32;
    const unsigned short* Qp = Q + (size_t)bh * S_LEN * HD;
    const unsigned short* Kp = Kg + (size_t)bh * S_LEN * HD;
    const unsigned short* Vp = Vt + (size_t)bh * HD * S_LEN;

    // persistent Q fragments: 2 n-tiles (32 q-rows) x 4 k-frags
    bf16x8 qf[2][4];
#pragma unroll
    for (int qn = 0; qn < 2; qn++)
#pragma unroll
        for (int kk = 0; kk < 4; kk++)
            qf[qn][kk] = *(const bf16x8*)(Qp + (size_t)(q0 + qn * 16 + c) * HD + kk * 32 + quad * 8);

    f32x4 zero = {0.f, 0.f, 0.f, 0.f};
    f32x4 o_acc[2][8];
#pragma unroll
    for (int qn = 0; qn < 2; qn++)
#pragma unroll
        for (int nt = 0; nt < 8; nt++) o_acc[qn][nt] = zero;
    float lsum[2] = {0.f, 0.f};

    for (int key0 = 0; key0 < S_LEN; key0 += 64) {
        // stage K[64][128] and Vt[128][64] chunks via async DMA, XOR-swizzled source
#pragma unroll
        for (int j = 0; j < 4; j++) {
            int fc = (wave * 4 + j) * 64 + lane;
            int rK = fc >> 4, cbK = (fc & 15) ^ (rK & 15);
            async16(Kp + (size_t)(key0 + rK) * HD + cbK * 8, Ksm + (wave * 4 + j) * 512);
            int rV = fc >> 3, cbV = (fc & 7) ^ (rV & 7);
            async16(Vp + (size_t)rV * S_LEN + key0 + cbV * 8, Vsm + (wave * 4 + j) * 512);
        }
        __syncthreads();

        // S^T = K * Q^T : M=key (4 tiles), N=qrow (2 tiles), K=d (4 frags)
        f32x4 sacc[4][2];
#pragma unroll
        for (int km = 0; km < 4; km++)
#pragma unroll
            for (int qn = 0; qn < 2; qn++) sacc[km][qn] = zero;
#pragma unroll
        for (int kk = 0; kk < 4; kk++) {
            bf16x8 kfr[4];
#pragma unroll
            for (int km = 0; km < 4; km++)
                kfr[km] = *(const bf16x8*)(Ksm + (km * 16 + c) * HD + (((kk * 4 + quad) ^ c)) * 8);
#pragma unroll
            for (int km = 0; km < 4; km++)
#pragma unroll
                for (int qn = 0; qn < 2; qn++)
                    sacc[km][qn] = __builtin_amdgcn_mfma_f32_16x16x32_bf16(kfr[km], qf[qn][kk],
                                                                           sacc[km][qn], 0, 0, 0);
        }

        // exp2 (scale pre-folded, no max subtraction), row-sum partials, pack P -> LDS
        // C-layout of S^T: lane holds qrow=c, keys km*16 + quad*4 + r (consecutive r!)
#pragma unroll
        for (int qn = 0; qn < 2; qn++) {
#pragma unroll
            for (int km = 0; km < 4; km++) {
                float e0 = exp2_fast(sacc[km][qn][0]);
                float e1 = exp2_fast(sacc[km][qn][1]);
                float e2 = exp2_fast(sacc[km][qn][2]);
                float e3 = exp2_fast(sacc[km][qn][3]);
                lsum[qn] += (e0 + e1) + (e2 + e3);
                uint2 pk;
                pk.x = pkbf(e0, e1);
                pk.y = pkbf(e2, e3);
                *(uint2*)(Psm + ((wave * 2 + qn) * 16 + c) * PKS + km * 16 + quad * 4) = pk;
            }
        }
        // intra-wave LDS write->read ordering (cross-lane): compiler fence + lgkmcnt(0)
        asm volatile("" ::: "memory");
        __builtin_amdgcn_s_waitcnt(0xc07f);  // lgkmcnt(0), vmcnt/expcnt unaffected
        asm volatile("" ::: "memory");

        // O += P * V : A=P [qrow][key], B=Vt [d][key]
#pragma unroll
        for (int kf = 0; kf < 2; kf++) {
            bf16x8 pf[2];
#pragma unroll
            for (int qn = 0; qn < 2; qn++)
                pf[qn] = *(const bf16x8*)(Psm + ((wave * 2 + qn) * 16 + c) * PKS + kf * 32 + quad * 8);
#pragma unroll
            for (int nt = 0; nt < 8; nt++) {
                bf16x8 vf = *(const bf16x8*)(Vsm + (nt * 16 + c) * 64 +
                                             (((kf * 4 + quad) ^ (c & 7))) * 8);
#pragma unroll
                for (int qn = 0; qn < 2; qn++)
                    o_acc[qn][nt] = __builtin_amdgcn_mfma_f32_16x16x32_bf16(pf[qn], vf,
                                                                            o_acc[qn][nt], 0, 0, 0);
            }
        }
        __syncthreads();  // protect Ksm/Vsm before next-iter DMA
    }

    // final: reduce lsum over the 4 quad-lanes (row = c), broadcast to C-layout rows
#pragma unroll
    for (int qn = 0; qn < 2; qn++) {
        lsum[qn] += __shfl_xor(lsum[qn], 16);
        lsum[qn] += __shfl_xor(lsum[qn], 32);
    }
    float inv[2][4];
#pragma unroll
    for (int qn = 0; qn < 2; qn++)
#pragma unroll
        for (int r = 0; r < 4; r++)
            inv[qn][r] = 1.0f / __shfl(lsum[qn], quad * 4 + r);

#pragma unroll
    for (int qn = 0; qn < 2; qn++) {
#pragma unroll
        for (int r = 0; r < 4; r++) {
            int srow = q0 + qn * 16 + quad * 4 + r;
            size_t base = ((size_t)(b * S_LEN + srow)) * HID + h * HD;
#pragma unroll
            for (int nt = 0; nt < 8; nt++)
                Aout[base + nt * 16 + c] = f2bf(o_acc[qn][nt][r] * inv[qn][r]);
        }
    }
}

extern "C" void kernel_launch(void* const* d_in, const int* in_sizes, int n_in,
                              void* d_out, int out_size, void* d_ws, size_t ws_size,
                              hipStream_t stream) {
    const float* hs   = (const float*)d_in[0];
    const float* cosp = (const float*)d_in[1];
    const float* sinp = (const float*)d_in[2];
    const float* Wq   = (const float*)d_in[3];
    const float* Wk   = (const float*)d_in[4];
    const float* Wv   = (const float*)d_in[5];
    const float* Wo   = (const float*)d_in[6];

    char* ws = (char*)d_ws;
    unsigned short* Xb = (unsigned short*)(ws);                      // 0-16 MB (reused as Aout)
    unsigned short* Qb = (unsigned short*)(ws + (16ull << 20));      // 16-32
    unsigned short* Kb = (unsigned short*)(ws + (32ull << 20));      // 32-48
    unsigned short* Vb = (unsigned short*)(ws + (48ull << 20));      // 48-64
    unsigned short* WT = (unsigned short*)(ws + (64ull << 20));      // 64-88 fused / 64-72 single

    const bool fused = ws_size >= (88ull << 20);

    if (fused) {
        // 1. cast + 3 weight transposes in one launch
        prep<<<dim3(64, 64, 4), 256, 0, stream>>>(hs, Wq, Wk, Wv, Xb, WT);
        // 2. fused QKV GEMM with RoPE epilogue (Q pre-scaled by log2e/sqrt(D))
        gemm_bt<0><<<dim3(48, 32), 256, 0, stream>>>(Xb, WT, Qb, Kb, Vb, nullptr,
                                                     cosp, sinp, 0);
        // 3. flash attention
        attn_kernel<<<dim3(16, 32), 256, 0, stream>>>(Qb, Kb, Vb, Xb /*Aout*/);
        // 4. Wo transpose into dead Qb region
        unsigned short* WoT = (unsigned short*)(ws + (16ull << 20));
        transpose_cast<<<dim3(64, 64), 256, 0, stream>>>(Wo, WoT);
        // 5. output GEMM, fp32 direct to d_out
        gemm_bt<2><<<dim3(16, 32), 256, 0, stream>>>(Xb, WoT, nullptr, nullptr, nullptr,
                                                     (float*)d_out, cosp, sinp, 0);
    } else {
        // fallback: 8 MB WT region, per-matrix GEMMs
        prep<<<dim3(64, 64, 1), 256, 0, stream>>>(hs, Wq, Wq, Wq, Xb, WT);
        // cast part of prep (z==3) missing in z=1 grid -> run cast via prep z block trick:
        // use a dedicated pass: z grid (64,64,1) only transposed Wq; do cast + others below.
        prep<<<dim3(64, 64, 4), 256, 0, stream>>>(hs, Wq, Wq, Wq, Xb, WT);  // cast + Wq^T
        gemm_bt<0><<<dim3(16, 32), 256, 0, stream>>>(Xb, WT, Qb, Kb, Vb, nullptr,
                                                     cosp, sinp, 0);
        transpose_cast<<<dim3(64, 64), 256, 0, stream>>>(Wk, WT);
        gemm_bt<0><<<dim3(16, 32), 256, 0, stream>>>(Xb, WT, Qb, Kb, Vb, nullptr,
                                                     cosp, sinp, 2048);
        transpose_cast<<<dim3(64, 64), 256, 0, stream>>>(Wv, WT);
        gemm_bt<0><<<dim3(16, 32), 256, 0, stream>>>(Xb, WT, Qb, Kb, Vb, nullptr,
                                                     cosp, sinp, 4096);
        attn_kernel<<<dim3(16, 32), 256, 0, stream>>>(Qb, Kb, Vb, Xb /*Aout*/);
        transpose_cast<<<dim3(64, 64), 256, 0, stream>>>(Wo, WT);
        gemm_bt<2><<<dim3(16, 32), 256, 0, stream>>>(Xb, WT, nullptr, nullptr, nullptr,
                                                     (float*)d_out, cosp, sinp, 0);
    }
}